// Round 3
// baseline (1532.008 us; speedup 1.0000x reference)
//
#include <hip/hip_runtime.h>

#define NV   200000      // occupied voxels
#define CC   128         // channels
#define KOFF 27          // 3x3x3 offsets

typedef unsigned short u16;
typedef __attribute__((ext_vector_type(4))) float f32x4;
typedef __attribute__((ext_vector_type(8))) short bf16x8;

__device__ __forceinline__ u16 f2bf(float f) {
    unsigned u = __float_as_uint(f);
    u += 0x7fffu + ((u >> 16) & 1u);          // RNE
    return (u16)(u >> 16);
}

// global -> LDS direct DMA, 16B/lane; LDS dest = wave-uniform base + lane*16
#define GLOAD16(gp, lp)                                                        \
    __builtin_amdgcn_global_load_lds(                                          \
        (const __attribute__((address_space(1))) void*)(gp),                   \
        (__attribute__((address_space(3))) void*)(lp), 16, 0, 0)

#define WAITV4()                                                               \
    do { asm volatile("s_waitcnt vmcnt(4)" ::: "memory");                      \
         __builtin_amdgcn_sched_barrier(0); } while (0)
#define WAITV0()                                                               \
    do { asm volatile("s_waitcnt vmcnt(0)" ::: "memory");                      \
         __builtin_amdgcn_sched_barrier(0); } while (0)
#define LGKM0()                                                                \
    do { asm volatile("s_waitcnt lgkmcnt(0)" ::: "memory");                    \
         __builtin_amdgcn_sched_barrier(0); } while (0)
#define BARRIER() asm volatile("s_barrier" ::: "memory")

// ---------------------------------------------------------------------------
__global__ void gmap_kernel(const int* __restrict__ iin,
                            const int* __restrict__ iout,
                            int* __restrict__ gmap) {
    int t = blockIdx.x * 256 + threadIdx.x;
    if (t >= KOFF * NV) return;
    int o = iout[t];
    if (o < NV) {
        int k = t / NV;
        gmap[k * NV + o] = iin[t];
    }
}

__global__ void cvt_kernel(const float* __restrict__ src,
                           u16* __restrict__ dst, int n4) {
    int i = blockIdx.x * 256 + threadIdx.x;
    if (i >= n4) return;
    float4 v = ((const float4*)src)[i];
    ushort4 o;
    o.x = f2bf(v.x); o.y = f2bf(v.y); o.z = f2bf(v.z); o.w = f2bf(v.w);
    ((ushort4*)dst)[i] = o;
}

// Wp[(k*nks+ks)*8 + cf][lane][j] = W[k][ks*32 + (lane>>4)*8 + j][cf*16 + (lane&15)]
__global__ void packw_kernel(const float* __restrict__ W,
                             u16* __restrict__ Wp, int cin, int total) {
    int t = blockIdx.x * 256 + threadIdx.x;
    if (t >= total) return;
    int j  = t & 7;
    int l  = (t >> 3) & 63;
    int cf = (t >> 9) & 7;
    int sk = t >> 12;
    int nks = cin >> 5;
    int k  = sk / nks;
    int ks = sk - k * nks;
    int kpos = ks * 32 + (l >> 4) * 8 + j;
    int col  = cf * 16 + (l & 15);
    Wp[t] = f2bf(W[((size_t)k * cin + kpos) * CC + col]);
}

// ---------------------------------------------------------------------------
// Gathered sparse conv, 2-phase-per-K-tile pipelined schedule:
// 256x128 tile / block, 8 waves (64x64 each), BK=64.
// A: ring-3 LDS (distance-2 prefetch), B: ring-2 LDS, gmap: LDS-resident table.
// One counted vmcnt(4) per K-tile; raw s_barrier (no drain) throughout.
template <int NKT, int ACT, int OUT16>
__global__ __launch_bounds__(512, 2)
void conv_kernel(const u16* __restrict__ f0, const u16* __restrict__ f1,
                 const u16* __restrict__ Wp, const float* __restrict__ bias,
                 const int* __restrict__ gmap, const u16* __restrict__ zrow,
                 float* __restrict__ out32, u16* __restrict__ out16) {
    constexpr int NT = KOFF * NKT;          // 54 or 108 K-tiles of 64

    __shared__ u16 Ab[3][256 * 64];         // 96 KiB, chunk-swizzled
    __shared__ u16 Bb[2][16 * 512];         // 32 KiB, fragment-linear
    __shared__ int gmT[KOFF * 256 + 64];    // 27.25 KiB gather table

    const int tid = threadIdx.x;
    const int l   = tid & 63;
    const int w   = tid >> 6;               // 8 waves
    const int wr  = w >> 1, wc = w & 1;     // 4M x 2N
    const int r0  = blockIdx.x * 256;

    const int lrow8 = l >> 3;
    const int csw   = (l & 7) ^ lrow8;      // pre-swizzled source chunk
    const u16* zsrc = zrow + csw * 8;

    // ---- preload gmTab: gmT[k*256+row] = gmap[k*NV + r0 + row] ----
    // 27*256 ints = 1728 16B-chunks; chunk c -> k=c>>6, rows (c&63)*4..+3
#pragma unroll
    for (int p = 0; p < 3; ++p) {
        int c = p * 512 + w * 64 + l;
        const int* src = gmap + (size_t)(c >> 6) * NV + r0 + (c & 63) * 4;
        GLOAD16(src, (char*)gmT + (size_t)(p * 512 + w * 64) * 16);
    }
    if (w < 3) {
        int c = 1536 + w * 64 + l;
        const int* src = gmap + (size_t)(c >> 6) * NV + r0 + (c & 63) * 4;
        GLOAD16(src, (char*)gmT + (size_t)(1536 + w * 64) * 16);
    }

    int rowl[4];
#pragma unroll
    for (int i = 0; i < 4; ++i) rowl[i] = i * 64 + w * 8 + lrow8;

    float bcol[4];
#pragma unroll
    for (int n = 0; n < 4; ++n) bcol[n] = bias[wc * 64 + n * 16 + (l & 15)];

    f32x4 acc[4][4] = {};

    auto readGm = [&](int t, int* gm) {
        const int* g = &gmT[(t / NKT) * 256];
#pragma unroll
        for (int i = 0; i < 4; ++i) gm[i] = g[rowl[i]];
    };

    auto stageA = [&](int t, int buf, const int* gm) {
        int kt = t % NKT;
        const u16* fb;
        int coloff;
        if constexpr (NKT == 4) {           // concat: kt 0,1 = x, kt 2,3 = h
            fb = (kt < 2) ? f0 : f1;  coloff = (kt & 1) * 64;
        } else {
            fb = f0;                  coloff = kt * 64;
        }
#pragma unroll
        for (int i = 0; i < 4; ++i) {
            int g = gm[i];
            const u16* src = (g >= 0)
                ? fb + ((size_t)g << 7) + coloff + csw * 8 : zsrc;
            GLOAD16(src, &Ab[buf][(i * 64 + w * 8) * 64]);
        }
    };

    auto stageB = [&](int t) {
        int k = t / NKT, kt = t % NKT, bb = t & 1;
        const u16* wsrc = Wp + ((size_t)(k * NKT + kt) * 16) * 512 + l * 8;
        GLOAD16(wsrc + (size_t)w * 512,       &Bb[bb][w * 512]);
        GLOAD16(wsrc + (size_t)(8 + w) * 512, &Bb[bb][(8 + w) * 512]);
    };

    auto readA = [&](int buf, int ks, bf16x8* a) {
#pragma unroll
        for (int m = 0; m < 4; ++m) {
            int row = wr * 64 + m * 16 + (l & 15);
            int ch  = (ks * 4 + (l >> 4)) ^ (row & 7);
            a[m] = *(const bf16x8*)&Ab[buf][row * 64 + ch * 8];
        }
    };

    auto readB = [&](int bb, int ks, bf16x8* b) {
#pragma unroll
        for (int n = 0; n < 4; ++n)
            b[n] = *(const bf16x8*)&Bb[bb][(ks * 8 + wc * 4 + n) * 512 + l * 8];
    };

    // ---- prologue: drain gmTab, then establish queue [A(0)4, B(0)2, A(1)4]
    WAITV0();
    BARRIER();
    {
        int gm0[4], gm1[4];
        readGm(0, gm0);
        readGm(1, gm1);
        stageA(0, 0, gm0);
        stageB(0);
        stageA(1, 1, gm1);
    }

    int cur = 0, sb = 2;
    for (int t = 0; t < NT; ++t) {
        // invariant queue at entry: [A(t)4, B(t)2, A(t+1)4] (last iter: [A,B])
        if (t == NT - 1) { WAITV0(); } else { WAITV4(); }
        BARRIER();                           // all waves' stage(t) visible

        // ---- phase 0 (ks=0) ----
        if (t + 1 < NT) stageB(t + 1);
        int gmN[4];
        if (t + 2 < NT) readGm(t + 2, gmN);
        {
            bf16x8 a[4], b[4];
            readA(cur, 0, a);
            readB(t & 1, 0, b);
            BARRIER();
            LGKM0();
            __builtin_amdgcn_s_setprio(1);
#pragma unroll
            for (int m = 0; m < 4; ++m)
#pragma unroll
                for (int n = 0; n < 4; ++n)
                    acc[m][n] = __builtin_amdgcn_mfma_f32_16x16x32_bf16(
                        a[m], b[n], acc[m][n], 0, 0, 0);
            __builtin_amdgcn_s_setprio(0);
            BARRIER();
        }

        // ---- phase 1 (ks=1) ----
        if (t + 2 < NT) stageA(t + 2, sb, gmN);
        {
            bf16x8 a[4], b[4];
            readA(cur, 1, a);
            readB(t & 1, 1, b);
            BARRIER();
            LGKM0();
            __builtin_amdgcn_s_setprio(1);
#pragma unroll
            for (int m = 0; m < 4; ++m)
#pragma unroll
                for (int n = 0; n < 4; ++n)
                    acc[m][n] = __builtin_amdgcn_mfma_f32_16x16x32_bf16(
                        a[m], b[n], acc[m][n], 0, 0, 0);
            __builtin_amdgcn_s_setprio(0);
            BARRIER();
        }

        cur = (cur == 2) ? 0 : cur + 1;
        sb  = (sb  == 2) ? 0 : sb  + 1;
    }

    // epilogue: C/D layout col=lane&15, row=(lane>>4)*4+reg  [m89-verified]
#pragma unroll
    for (int m = 0; m < 4; ++m) {
        int rbase = r0 + wr * 64 + m * 16 + (l >> 4) * 4;
#pragma unroll
        for (int i = 0; i < 4; ++i) {
            int row = rbase + i;
            if (row < NV) {
#pragma unroll
                for (int n = 0; n < 4; ++n) {
                    float v = acc[m][n][i] + bcol[n];
                    if constexpr (ACT) v = fmaxf(v, 0.f);
                    int col = wc * 64 + n * 16 + (l & 15);
                    if constexpr (OUT16) out16[(size_t)row * CC + col] = f2bf(v);
                    else                 out32[(size_t)row * CC + col] = v;
                }
            }
        }
    }
}

// ---------------------------------------------------------------------------
extern "C" void kernel_launch(void* const* d_in, const int* in_sizes, int n_in,
                              void* d_out, int out_size, void* d_ws, size_t ws_size,
                              hipStream_t stream) {
    (void)in_sizes; (void)n_in; (void)out_size; (void)ws_size;
    const float* xF  = (const float*)d_in[0];
    const float* xgF = (const float*)d_in[1];
    const float* W0  = (const float*)d_in[2];
    const float* b0  = (const float*)d_in[3];
    const float* W1  = (const float*)d_in[4];
    const float* b1  = (const float*)d_in[5];
    const float* W2  = (const float*)d_in[6];
    const float* b2  = (const float*)d_in[7];
    const int* iin   = (const int*)d_in[8];
    const int* iout  = (const int*)d_in[9];
    float* out = (float*)d_out;
    char* ws = (char*)d_ws;

    size_t off = 0;
    int* gmap  = (int*)(ws + off);  off += ((size_t)KOFF * NV + 512) * 4;  // pad = -1
    u16* zrow  = (u16*)(ws + off);  off += 256;
    u16* F0    = (u16*)(ws + off);  off += (size_t)NV * CC * 2;     // xg16 -> h1
    u16* F1    = (u16*)(ws + off);  off += (size_t)NV * CC * 2;     // h0
    u16* F2    = (u16*)(ws + off);  off += (size_t)NV * CC * 2;     // x16
    u16* WP0   = (u16*)(ws + off);  off += (size_t)KOFF * 128 * 128 * 2;
    u16* WP1   = (u16*)(ws + off);  off += (size_t)KOFF * 128 * 128 * 2;
    u16* WP2   = (u16*)(ws + off);  off += (size_t)KOFF * 256 * 128 * 2;

    (void)hipMemsetAsync(gmap, 0xFF, ((size_t)KOFF * NV + 512) * 4, stream);  // -1
    (void)hipMemsetAsync(zrow, 0, 256, stream);

    gmap_kernel<<<(KOFF * NV + 255) / 256, 256, 0, stream>>>(iin, iout, gmap);
    cvt_kernel<<<(NV * CC / 4 + 255) / 256, 256, 0, stream>>>(xgF, F0, NV * CC / 4);
    cvt_kernel<<<(NV * CC / 4 + 255) / 256, 256, 0, stream>>>(xF,  F2, NV * CC / 4);
    packw_kernel<<<(KOFF * 128 * 128 + 255) / 256, 256, 0, stream>>>(W0, WP0, 128, KOFF * 128 * 128);
    packw_kernel<<<(KOFF * 128 * 128 + 255) / 256, 256, 0, stream>>>(W1, WP1, 128, KOFF * 128 * 128);
    packw_kernel<<<(KOFF * 256 * 128 + 255) / 256, 256, 0, stream>>>(W2, WP2, 256, KOFF * 256 * 128);

    const int NB = (NV + 255) / 256;   // 782
    // conv0: h0 = xg (*) W0 + b0            -> F1 (bf16)
    conv_kernel<2, 0, 1><<<NB, 512, 0, stream>>>(F0, F0, WP0, b0, gmap, zrow, nullptr, F1);
    // conv1: h1 = relu(h0 (*) W1 + b1)      -> F0 (bf16)
    conv_kernel<2, 1, 1><<<NB, 512, 0, stream>>>(F1, F1, WP1, b1, gmap, zrow, nullptr, F0);
    // conv2: out = [x | h1] (*) W2 + b2     -> d_out (fp32)
    conv_kernel<4, 0, 0><<<NB, 512, 0, stream>>>(F2, F0, WP2, b2, gmap, zrow, out, nullptr);
}

// Round 4
// 774.237 us; speedup vs baseline: 1.9787x; 1.9787x over previous
//
#include <hip/hip_runtime.h>

#define NV   200000      // occupied voxels
#define CC   128         // channels
#define KOFF 27          // 3x3x3 offsets

typedef unsigned short u16;
typedef __attribute__((ext_vector_type(4))) float f32x4;
typedef __attribute__((ext_vector_type(8))) short bf16x8;

__device__ __forceinline__ u16 f2bf(float f) {
    unsigned u = __float_as_uint(f);
    u += 0x7fffu + ((u >> 16) & 1u);          // RNE
    return (u16)(u >> 16);
}

// global -> LDS direct DMA, 16B per lane; LDS dest = uniform base + lane*16
#define GLOAD16(gp, lp)                                                        \
    __builtin_amdgcn_global_load_lds(                                          \
        (const __attribute__((address_space(1))) void*)(gp),                   \
        (__attribute__((address_space(3))) void*)(lp), 16, 0, 0)

// ---------------------------------------------------------------------------
// gmap[k][i] = input row feeding output row i at offset k, or -1.
// out_idx entries are distinct per k, so this scatter is race-free.
__global__ void gmap_kernel(const int* __restrict__ iin,
                            const int* __restrict__ iout,
                            int* __restrict__ gmap) {
    int t = blockIdx.x * 256 + threadIdx.x;
    if (t >= KOFF * NV) return;
    int o = iout[t];
    if (o < NV) {
        int k = t / NV;
        gmap[k * NV + o] = iin[t];
    }
}

// fp32 -> bf16, 4 elems/thread
__global__ void cvt_kernel(const float* __restrict__ src,
                           u16* __restrict__ dst, int n4) {
    int i = blockIdx.x * 256 + threadIdx.x;
    if (i >= n4) return;
    float4 v = ((const float4*)src)[i];
    ushort4 o;
    o.x = f2bf(v.x); o.y = f2bf(v.y); o.z = f2bf(v.z); o.w = f2bf(v.w);
    ((ushort4*)dst)[i] = o;
}

// Pack W[k][kpos][col] fp32 into fragment-linear bf16:
// Wp[(k*nks+ks)*8 + cf][lane][j] = W[k][ks*32 + (lane>>4)*8 + j][cf*16 + (lane&15)]
__global__ void packw_kernel(const float* __restrict__ W,
                             u16* __restrict__ Wp, int cin, int total) {
    int t = blockIdx.x * 256 + threadIdx.x;
    if (t >= total) return;
    int j  = t & 7;
    int l  = (t >> 3) & 63;
    int cf = (t >> 9) & 7;
    int sk = t >> 12;                 // k*nks + ks
    int nks = cin >> 5;
    int k  = sk / nks;
    int ks = sk - k * nks;
    int kpos = ks * 32 + (l >> 4) * 8 + j;
    int col  = cf * 16 + (l & 15);
    Wp[t] = f2bf(W[((size_t)k * cin + kpos) * CC + col]);
}

// ---------------------------------------------------------------------------
// Gathered sparse conv: out[i] = bias + sum_k feat[gmap[k][i]] @ W[k]
// 128x128 tile / block, 4 waves (64x64 each), BK=32, double-buffered LDS.
// A-chunk swizzle: slot = row*4 + (c ^ ((row>>1)&3))  -- conflict-free on
// both the glds staging (linear dest) and the ds_read_b128 fragment reads
// (uniform 2 lanes per 4-bank group per 16-lane quarter). r1's (row&3)
// variant left a 2x conflict (SQ_LDS_BANK_CONFLICT 2.16e7).
template <int NKS, int ACT, int OUT16>
__global__ __launch_bounds__(256, 2)
void conv_kernel(const u16* __restrict__ f0, const u16* __restrict__ f1,
                 const u16* __restrict__ Wp, const float* __restrict__ bias,
                 const int* __restrict__ gmap, const u16* __restrict__ zrow,
                 float* __restrict__ out32, u16* __restrict__ out16) {
    constexpr int NSTEP = KOFF * NKS;

    // A: 512 chunks of 16B per buffer; chunk slot = row*4 + (c ^ ((row>>1)&3))
    __shared__ u16 Ab[2][512 * 8];
    // B: 8 col-frags x 64 lanes x 16B per buffer (fragment-linear)
    __shared__ u16 Bb[2][8][64][8];

    const int tid = threadIdx.x;
    const int l   = tid & 63;
    const int w   = tid >> 6;
    const int wr  = w >> 1, wc = w & 1;
    const int r0  = blockIdx.x * 128;

    // A staging geometry: wave w issues instrs j=2w,2w+1; instr j covers
    // slots j*64+l -> row = j*16 + (l>>2), sigma = l&3,
    // source chunk c = sigma ^ ((row>>1)&3) = (l&3) ^ ((l>>3)&3)
    const int qA  = (l & 3) ^ ((l >> 3) & 3);
    const int rA0 = 32 * w + (l >> 2);
    const int rA1 = rA0 + 16;

    float bcol[4];
#pragma unroll
    for (int c = 0; c < 4; ++c) bcol[c] = bias[wc * 64 + c * 16 + (l & 15)];

    f32x4 acc[4][4] = {};

    int gA, gB;                                   // gathered row ids (prefetched)
    auto loadGmap = [&](int s) {
        int k = s / NKS;
        int ra = r0 + rA0, rb = r0 + rA1;
        gA = (ra < NV) ? gmap[k * NV + ra] : -1;
        gB = (rb < NV) ? gmap[k * NV + rb] : -1;
    };

    auto stage = [&](int s, int buf) {
        int k = s / NKS, ks = s - k * NKS;
        const u16* base;
        int slice;
        if constexpr (NKS == 8) {                 // concat: slices 0-3 = x, 4-7 = h
            base  = (ks < 4) ? f0 : f1;
            slice = (ks & 3) * 32;
        } else {
            base  = f0;
            slice = ks * 32;
        }
        const u16* sA0 = (gA >= 0) ? base + (size_t)gA * CC + slice + qA * 8
                                   : zrow + qA * 8;
        const u16* sA1 = (gB >= 0) ? base + (size_t)gB * CC + slice + qA * 8
                                   : zrow + qA * 8;
        GLOAD16(sA0, &Ab[buf][(2 * w) * 64 * 8]);
        GLOAD16(sA1, &Ab[buf][(2 * w + 1) * 64 * 8]);
        const u16* wsrc = Wp + (((size_t)(k * NKS + ks) * 8 + 2 * w) * 512) + l * 8;
        GLOAD16(wsrc,       &Bb[buf][2 * w][0][0]);
        GLOAD16(wsrc + 512, &Bb[buf][2 * w + 1][0][0]);
    };

    auto compute = [&](int buf) {
        bf16x8 a[4], b[4];
        const int q = l >> 4;
#pragma unroll
        for (int rf = 0; rf < 4; ++rf) {
            int rl = wr * 64 + rf * 16 + (l & 15);
            int ci = rl * 4 + (q ^ ((rl >> 1) & 3));
            a[rf] = *(const bf16x8*)&Ab[buf][ci * 8];
        }
#pragma unroll
        for (int c = 0; c < 4; ++c)
            b[c] = *(const bf16x8*)&Bb[buf][wc * 4 + c][l][0];
#pragma unroll
        for (int rf = 0; rf < 4; ++rf)
#pragma unroll
            for (int c = 0; c < 4; ++c)
                acc[rf][c] = __builtin_amdgcn_mfma_f32_16x16x32_bf16(
                    a[rf], b[c], acc[rf][c], 0, 0, 0);
    };

    loadGmap(0);
    stage(0, 0);
    loadGmap(1);
    __syncthreads();

    int cur = 0;
    for (int s = 0; s < NSTEP; ++s) {
        if (s + 1 < NSTEP) {
            stage(s + 1, cur ^ 1);                // issue next-tile loads first
            if (s + 2 < NSTEP) loadGmap(s + 2);   // prefetch gather indices
        }
        compute(cur);
        __syncthreads();                          // vmcnt(0)+lgkmcnt(0)+barrier
        cur ^= 1;
    }

    // epilogue: C/D layout col=lane&15, row=(lane>>4)*4+reg  [m89-verified]
#pragma unroll
    for (int rf = 0; rf < 4; ++rf) {
        int rbase = r0 + wr * 64 + rf * 16 + (l >> 4) * 4;
#pragma unroll
        for (int i = 0; i < 4; ++i) {
            int row = rbase + i;
            if (row < NV) {
#pragma unroll
                for (int c = 0; c < 4; ++c) {
                    float v = acc[rf][c][i] + bcol[c];
                    if constexpr (ACT) v = fmaxf(v, 0.f);
                    int col = wc * 64 + c * 16 + (l & 15);
                    if constexpr (OUT16) out16[(size_t)row * CC + col] = f2bf(v);
                    else                 out32[(size_t)row * CC + col] = v;
                }
            }
        }
    }
}

// ---------------------------------------------------------------------------
extern "C" void kernel_launch(void* const* d_in, const int* in_sizes, int n_in,
                              void* d_out, int out_size, void* d_ws, size_t ws_size,
                              hipStream_t stream) {
    (void)in_sizes; (void)n_in; (void)out_size; (void)ws_size;
    const float* xF  = (const float*)d_in[0];
    const float* xgF = (const float*)d_in[1];
    const float* W0  = (const float*)d_in[2];
    const float* b0  = (const float*)d_in[3];
    const float* W1  = (const float*)d_in[4];
    const float* b1  = (const float*)d_in[5];
    const float* W2  = (const float*)d_in[6];
    const float* b2  = (const float*)d_in[7];
    const int* iin   = (const int*)d_in[8];
    const int* iout  = (const int*)d_in[9];
    float* out = (float*)d_out;
    char* ws = (char*)d_ws;

    size_t off = 0;
    int* gmap  = (int*)(ws + off);  off += (size_t)KOFF * NV * 4;   // 21.6 MB
    u16* zrow  = (u16*)(ws + off);  off += 256;
    u16* F0    = (u16*)(ws + off);  off += (size_t)NV * CC * 2;     // xg16 -> h1
    u16* F1    = (u16*)(ws + off);  off += (size_t)NV * CC * 2;     // h0
    u16* F2    = (u16*)(ws + off);  off += (size_t)NV * CC * 2;     // x16
    u16* WP0   = (u16*)(ws + off);  off += (size_t)KOFF * 128 * 128 * 2;
    u16* WP1   = (u16*)(ws + off);  off += (size_t)KOFF * 128 * 128 * 2;
    u16* WP2   = (u16*)(ws + off);  off += (size_t)KOFF * 256 * 128 * 2;
    // total ~178.7 MB of d_ws

    (void)hipMemsetAsync(gmap, 0xFF, (size_t)KOFF * NV * 4, stream);  // -1
    (void)hipMemsetAsync(zrow, 0, 256, stream);

    gmap_kernel<<<(KOFF * NV + 255) / 256, 256, 0, stream>>>(iin, iout, gmap);
    cvt_kernel<<<(NV * CC / 4 + 255) / 256, 256, 0, stream>>>(xgF, F0, NV * CC / 4);
    cvt_kernel<<<(NV * CC / 4 + 255) / 256, 256, 0, stream>>>(xF,  F2, NV * CC / 4);
    packw_kernel<<<(KOFF * 128 * 128 + 255) / 256, 256, 0, stream>>>(W0, WP0, 128, KOFF * 128 * 128);
    packw_kernel<<<(KOFF * 128 * 128 + 255) / 256, 256, 0, stream>>>(W1, WP1, 128, KOFF * 128 * 128);
    packw_kernel<<<(KOFF * 256 * 128 + 255) / 256, 256, 0, stream>>>(W2, WP2, 256, KOFF * 256 * 128);

    const int NB = (NV + 127) / 128;   // 1563
    // conv0: h0 = xg (*) W0 + b0            -> F1 (bf16)
    conv_kernel<4, 0, 1><<<NB, 256, 0, stream>>>(F0, F0, WP0, b0, gmap, zrow, nullptr, F1);
    // conv1: h1 = relu(h0 (*) W1 + b1)      -> F0 (bf16)
    conv_kernel<4, 1, 1><<<NB, 256, 0, stream>>>(F1, F1, WP1, b1, gmap, zrow, nullptr, F0);
    // conv2: out = [x | h1] (*) W2 + b2     -> d_out (fp32)
    conv_kernel<8, 0, 0><<<NB, 256, 0, stream>>>(F2, F0, WP2, b2, gmap, zrow, out, nullptr);
}